// Round 1
// 585.496 us; speedup vs baseline: 1.6992x; 1.6992x over previous
//
#include <hip/hip_runtime.h>
#include <cstdint>

// Problem: B=64, T=512, I=K=1024, H=1024.
// Reference collapses to: rtot_z = h0@R_z^T + rb_z + b_z  (z in {f,i,g}; o-gate dead)
//   gate_z[m',h] = x_perm[m'] . W_z^T + rtot_z[b,h]   with m' = t*64 + b
//   c = sig(f)*c0 + sig(i)*tanh(g); hidden[h, m'] = tanh(c); last-t -> h_last, c_last.
//
// v2 this round:
//   1. cvt_kernel: x -> bf16 ws copy PERMUTED to m'-major; Wf/Wi/Wg -> bf16 ws.
//      (moves fp32->bf16 conversion out of the GEMM hot loop; enables global_load_lds)
//   2. rprep2: tiled/coalesced fp32 rprep (old one was ~248us latency-bound).
//   3. lstm_main2: m97-structure fused GEMM: global_load_lds width-16 staging,
//      BK=64, LDS XOR swizzle (pre-swizzled global src + swizzled ds_read),
//      XCD-pinned block swizzle (each XCD owns 2 h-tiles -> W resident in L2).
//   Fallback to v1 kernels if ws_size too small.

typedef short s16x8 __attribute__((ext_vector_type(8)));
typedef short s16x4 __attribute__((ext_vector_type(4)));
typedef float f32x4 __attribute__((ext_vector_type(4)));

static __device__ __forceinline__ float bf2f(unsigned short u) {
    union { unsigned int i; float f; } v; v.i = ((unsigned int)u) << 16; return v.f;
}
static __device__ __forceinline__ unsigned short f2bf(float f) {
    union { float f; unsigned int i; } v; v.f = f;
    unsigned int u = v.i;
    return (unsigned short)((u + 0x7fffu + ((u >> 16) & 1u)) >> 16);
}
static __device__ __forceinline__ float sigm_(float x) { return 1.0f / (1.0f + __expf(-x)); }
static __device__ __forceinline__ float tanh_(float x) { return 1.0f - 2.0f / (1.0f + __expf(2.0f * x)); }

// Detect fp32 vs bf16 storage (wave-uniform, deterministic).
static __device__ __forceinline__ int detect_f32(const void* x) {
    const unsigned int* u = (const unsigned int*)x;
    int c = 0;
#pragma unroll
    for (int i = 0; i < 16; ++i) {
        unsigned int e = (u[i] >> 23) & 255u;
        c += (e >= 100u && e <= 140u) ? 1 : 0;
    }
    return c >= 8;
}

static __device__ __forceinline__ float ldsc(const void* p, int i, int f32) {
    return f32 ? ((const float*)p)[i] : bf2f(((const unsigned short*)p)[i]);
}

static __device__ __forceinline__ float4 load4f(const void* p, size_t eoff, int f32) {
    if (f32) return *(const float4*)((const float*)p + eoff);
    s16x4 v = *(const s16x4*)((const unsigned short*)p + eoff);
    return make_float4(bf2f((unsigned short)v[0]), bf2f((unsigned short)v[1]),
                       bf2f((unsigned short)v[2]), bf2f((unsigned short)v[3]));
}

// 16B direct global->LDS (DMA, no VGPR roundtrip). LDS dest must be linear in
// lane order within each wave (wave-uniform base + lane*16) -- caller guarantees.
static __device__ __forceinline__ void gl_lds16(const void* g, void* l) {
    __builtin_amdgcn_global_load_lds(
        (const __attribute__((address_space(1))) unsigned int*)g,
        (__attribute__((address_space(3))) unsigned int*)l, 16, 0, 0);
}

// ---------------- convert kernel: x (permute to m'-major) + W -> bf16 ws ----------------
// rows 0..32767: x row r = (b,t) -> xb[t*64+b];  rows 32768..35839: W rows (3 gates).
// Each block: 2 rows, 128 threads/row, 8 elems/thread.
__global__ __launch_bounds__(256) void cvt_kernel(
    const void* __restrict__ x,
    const void* __restrict__ Wf, const void* __restrict__ Wi, const void* __restrict__ Wg,
    unsigned short* __restrict__ xb, unsigned short* __restrict__ wb)
{
    const int f32 = detect_f32(x);
    const int tid = threadIdx.x;
    const int r = blockIdx.x * 2 + (tid >> 7);
    const int c = (tid & 127) << 3;
    const void* src;
    size_t soff;
    unsigned short* dst;
    if (r < 32768) {
        const int b = r >> 9, t = r & 511;
        src = x;
        soff = ((size_t)r << 10) + c;
        dst = xb + (((size_t)((t << 6) + b)) << 10) + c;
    } else {
        const int wr = r - 32768;            // 0..3071
        const int g = wr >> 10;
        src = (g == 0) ? Wf : (g == 1) ? Wi : Wg;
        soff = ((size_t)(wr & 1023) << 10) + c;
        dst = wb + ((size_t)wr << 10) + c;
    }
    if (f32) {
        const float* s = (const float*)src + soff;
        float4 u0 = *(const float4*)s;
        float4 u1 = *(const float4*)(s + 4);
        s16x8 v;
        v[0] = (short)f2bf(u0.x); v[1] = (short)f2bf(u0.y);
        v[2] = (short)f2bf(u0.z); v[3] = (short)f2bf(u0.w);
        v[4] = (short)f2bf(u1.x); v[5] = (short)f2bf(u1.y);
        v[6] = (short)f2bf(u1.z); v[7] = (short)f2bf(u1.w);
        *(s16x8*)dst = v;
    } else {
        *(s16x8*)dst = *(const s16x8*)((const unsigned short*)src + soff);
    }
}

// ---------------- rprep v2: rt[z][b][h] = h0[b].R_z[h] + rb_z[h] + b_z[h], fp32 ----------
// grid (64, 3): block = gate z, 16 h rows, all 64 b. Coalesced LDS-tiled.
__global__ __launch_bounds__(256) void rprep2(
    const void* __restrict__ xdet,
    const void* __restrict__ h0,
    const void* __restrict__ Rf, const void* __restrict__ rbf, const void* __restrict__ bf_,
    const void* __restrict__ Ri, const void* __restrict__ rbi, const void* __restrict__ bi_,
    const void* __restrict__ Rg, const void* __restrict__ rbg, const void* __restrict__ bg_,
    float* __restrict__ rt)
{
    const int f32 = detect_f32(xdet);
    const int z = blockIdx.y;
    const int hb = blockIdx.x * 16;
    __shared__ float h0l[64][132];   // +4 pad: b-rows 2-way at worst (free)
    __shared__ float Rl[16][132];
    const void* R  = (z == 0) ? Rf  : (z == 1) ? Ri  : Rg;
    const void* rb = (z == 0) ? rbf : (z == 1) ? rbi : rbg;
    const void* bb = (z == 0) ? bf_ : (z == 1) ? bi_ : bg_;
    const int tid = threadIdx.x;
    const int hl = tid >> 4;         // 0..15
    const int bq = tid & 15;         // b = bq + 16j
    float acc[4] = {0.f, 0.f, 0.f, 0.f};

    for (int k0 = 0; k0 < 1024; k0 += 128) {
        // stage h0 chunk: 64 x 128 = 2048 float4, 8/thread, coalesced
#pragma unroll
        for (int i = 0; i < 8; ++i) {
            int lin = i * 256 + tid;
            int r = lin >> 5, c4 = lin & 31;
            *(float4*)&h0l[r][c4 * 4] = load4f(h0, (size_t)r * 1024 + k0 + c4 * 4, f32);
        }
        // stage R chunk: 16 x 128 = 512 float4, 2/thread
#pragma unroll
        for (int i = 0; i < 2; ++i) {
            int lin = i * 256 + tid;
            int r = lin >> 5, c4 = lin & 31;
            *(float4*)&Rl[r][c4 * 4] = load4f(R, (size_t)(hb + r) * 1024 + k0 + c4 * 4, f32);
        }
        __syncthreads();
#pragma unroll 8
        for (int k4 = 0; k4 < 32; ++k4) {
            float4 rv = *(const float4*)&Rl[hl][k4 * 4];
#pragma unroll
            for (int j = 0; j < 4; ++j) {
                float4 hv = *(const float4*)&h0l[bq + j * 16][k4 * 4];
                acc[j] += rv.x * hv.x + rv.y * hv.y + rv.z * hv.z + rv.w * hv.w;
            }
        }
        __syncthreads();
    }
    float extra = ldsc(rb, hb + hl, f32) + ldsc(bb, hb + hl, f32);
    float* outz = rt + (size_t)z * 65536;
#pragma unroll
    for (int j = 0; j < 4; ++j)
        outz[(size_t)(bq + j * 16) * 1024 + hb + hl] = acc[j] + extra;
}

// ---------------- main fused GEMM v2 ----------------
// Tile 128 m' x 64 h x 3 gates, BK=64, 4 waves 2x2. global_load_lds staging with
// XOR swizzle: LDS linear dest, inverse-swizzled global src, swizzled ds_read.
__global__ __launch_bounds__(256, 2) void lstm_main2(
    const void* __restrict__ x,                  // dtype detect only
    const void* __restrict__ c0,
    const unsigned short* __restrict__ xb,       // [32768][1024] bf16, m'-major
    const unsigned short* __restrict__ wb,       // [3][1024][1024] bf16
    const float* __restrict__ rt,
    void* __restrict__ dout)
{
    // A 128x64 (16KB) | Bf/Bi/Bg 64x64 (8KB each) = 40960 B
    // epilogue transpose reuses smem: fp32 64x528 = 33792 B
    __shared__ __align__(16) unsigned char smem[40960];

    const int f32 = detect_f32(x);
    const int tid  = threadIdx.x;
    const int lane = tid & 63;
    const int w    = tid >> 6;
    const int wm   = w >> 1;
    const int wn   = w & 1;
    const int col  = lane & 15;
    const int quad = lane >> 4;

    // XCD-pinning block swizzle: linear dispatch id L; XCD = L%8 owns h-tiles {2x,2x+1};
    // the 16 h-blocks of one m-tile dispatch consecutively (A fetched once per XCD-L2).
    const int L    = blockIdx.x + (blockIdx.y << 4);   // grid (16, 256)
    const int xcd  = L & 7;
    const int s    = L >> 3;
    const int hblk = (xcd << 1) | (s & 1);
    const int mblk = s >> 1;
    const int m0   = mblk << 7;
    const int h0t  = hblk << 6;

    // staging descriptors: 16B chunks, LDS linear, global source pre-swizzled
    int   cA[4]; size_t gA[4];
#pragma unroll
    for (int i = 0; i < 4; ++i) {
        const int ci = tid + (i << 8);
        const int row = ci >> 3, kc = ci & 7;
        cA[i] = ci << 4;
        gA[i] = ((size_t)(m0 + row) << 10) + (size_t)((kc ^ (row & 7)) << 3);
    }
    int   cB[2]; size_t gB[2];
#pragma unroll
    for (int i = 0; i < 2; ++i) {
        const int ci = tid + (i << 8);
        const int row = ci >> 3, kc = ci & 7;
        cB[i] = ci << 4;
        gB[i] = ((size_t)(h0t + row) << 10) + (size_t)((kc ^ (row & 7)) << 3);
    }

    // fragment read bases (bytes); rows of 128 B; XOR bits 4-6 by row&7 (= col&7)
    const int xbits = (col & 7) << 4;
    int aRow[4], bRow[2];
#pragma unroll
    for (int mi = 0; mi < 4; ++mi) aRow[mi] = (wm * 64 + mi * 16 + col) << 7;
#pragma unroll
    for (int ni = 0; ni < 2; ++ni) bRow[ni] = (wn * 32 + ni * 16 + col) << 7;

    const unsigned short* wf = wb;
    const unsigned short* wi = wb + 1048576;
    const unsigned short* wg = wb + 2097152;

    f32x4 aF[4][2], aI[4][2], aG[4][2];
#pragma unroll
    for (int mi = 0; mi < 4; ++mi)
#pragma unroll
        for (int ni = 0; ni < 2; ++ni) {
            aF[mi][ni] = (f32x4)0.f; aI[mi][ni] = (f32x4)0.f; aG[mi][ni] = (f32x4)0.f;
        }

    for (int kt = 0; kt < 16; ++kt) {
        const size_t k0 = (size_t)kt << 6;
#pragma unroll
        for (int i = 0; i < 4; ++i)
            gl_lds16(xb + gA[i] + k0, smem + cA[i]);
#pragma unroll
        for (int i = 0; i < 2; ++i) {
            gl_lds16(wf + gB[i] + k0, smem + 16384 + cB[i]);
            gl_lds16(wi + gB[i] + k0, smem + 24576 + cB[i]);
            gl_lds16(wg + gB[i] + k0, smem + 32768 + cB[i]);
        }
        __syncthreads();                        // drains vmcnt -> LDS ready
#pragma unroll
        for (int kh = 0; kh < 2; ++kh) {
            const int cb = (((kh << 6) + (quad << 4)) ^ xbits);
            s16x8 av[4], bfv[2], biv[2], bgv[2];
#pragma unroll
            for (int mi = 0; mi < 4; ++mi)
                av[mi] = *(const s16x8*)(smem + aRow[mi] + cb);
#pragma unroll
            for (int ni = 0; ni < 2; ++ni) {
                bfv[ni] = *(const s16x8*)(smem + 16384 + bRow[ni] + cb);
                biv[ni] = *(const s16x8*)(smem + 24576 + bRow[ni] + cb);
                bgv[ni] = *(const s16x8*)(smem + 32768 + bRow[ni] + cb);
            }
#pragma unroll
            for (int mi = 0; mi < 4; ++mi)
#pragma unroll
                for (int ni = 0; ni < 2; ++ni) {
                    aF[mi][ni] = __builtin_amdgcn_mfma_f32_16x16x32_bf16(av[mi], bfv[ni], aF[mi][ni], 0, 0, 0);
                    aI[mi][ni] = __builtin_amdgcn_mfma_f32_16x16x32_bf16(av[mi], biv[ni], aI[mi][ni], 0, 0, 0);
                    aG[mi][ni] = __builtin_amdgcn_mfma_f32_16x16x32_bf16(av[mi], bgv[ni], aG[mi][ni], 0, 0, 0);
                }
        }
        __syncthreads();
    }

    // ---- epilogue (identical math to v1) ----
    const float* rtF = rt;
    const float* rtI = rt + 65536;
    const float* rtG = rt + 131072;
    unsigned short* outHb = (unsigned short*)dout;
    unsigned short* outHlb = outHb + 33554432;
    unsigned short* outClb = outHlb + 65536;
    float* outHf = (float*)dout;
    float* outHlf = outHf + 33554432;
    float* outClf = outHlf + 65536;

#pragma unroll
    for (int mi = 0; mi < 4; ++mi) {
#pragma unroll
        for (int ni = 0; ni < 2; ++ni) {
            const int hl = wn * 32 + ni * 16 + col;
            const int h  = h0t + hl;
            const int mbase = wm * 64 + mi * 16 + quad * 4;
            s16x4 packb;
            float4 packf;
#pragma unroll
            for (int r = 0; r < 4; ++r) {
                const int mg = m0 + mbase + r;
                const int b  = mg & 63;
                const int idx = b * 1024 + h;
                float pf = aF[mi][ni][r] + rtF[idx];
                float pi = aI[mi][ni][r] + rtI[idx];
                float pg = aG[mi][ni][r] + rtG[idx];
                float fv = sigm_(pf);
                float iv = sigm_(pi);
                float gv = tanh_(pg);
                float cv = fv * ldsc(c0, idx, f32) + iv * gv;
                float hv = tanh_(cv);
                if (r == 0) { packf.x = hv; } else if (r == 1) { packf.y = hv; }
                else if (r == 2) { packf.z = hv; } else { packf.w = hv; }
                packb[r] = (short)f2bf(hv);
                if ((mg >> 6) == 511) {
                    if (f32) { outHlf[idx] = hv; outClf[idx] = cv; }
                    else     { outHlb[idx] = f2bf(hv); outClb[idx] = f2bf(cv); }
                }
            }
            if (f32) {
                float* ldsTf = (float*)(smem + (size_t)hl * 528);
                *(float4*)(ldsTf + mbase) = packf;
            } else {
                *(s16x4*)(smem + (size_t)hl * 272 + mbase * 2) = packb;
            }
        }
    }
    __syncthreads();

    const int hl = tid >> 2;
    const int ch = tid & 3;
    if (f32) {
        float* obase = outHf + (size_t)(h0t + hl) * 32768 + m0 + ch * 32;
        const unsigned char* trow = smem + (size_t)hl * 528 + ch * 128;
#pragma unroll
        for (int j = 0; j < 8; ++j)
            *(float4*)(obase + j * 4) = *(const float4*)(trow + j * 16);
    } else {
        unsigned short* obase = outHb + (size_t)(h0t + hl) * 32768 + m0 + ch * 32;
        const unsigned char* trow = smem + (size_t)hl * 272 + ch * 64;
#pragma unroll
        for (int j = 0; j < 4; ++j)
            *(s16x8*)(obase + j * 8) = *(const s16x8*)(trow + j * 16);
    }
}

// ================= v1 fallback (workspace too small) =================
static __device__ __forceinline__ void stage8(const void* base, size_t eoff, short* dst, int f32) {
    if (f32) {
        const float* s = (const float*)base + eoff;
        float4 u0 = *(const float4*)s;
        float4 u1 = *(const float4*)(s + 4);
        s16x8 v;
        v[0] = (short)f2bf(u0.x); v[1] = (short)f2bf(u0.y);
        v[2] = (short)f2bf(u0.z); v[3] = (short)f2bf(u0.w);
        v[4] = (short)f2bf(u1.x); v[5] = (short)f2bf(u1.y);
        v[6] = (short)f2bf(u1.z); v[7] = (short)f2bf(u1.w);
        *(s16x8*)dst = v;
    } else {
        *(s16x8*)dst = *(const s16x8*)((const unsigned short*)base + eoff);
    }
}

__global__ __launch_bounds__(256) void rprep_kernel(
    const void* __restrict__ xdet,
    const void* __restrict__ h0,
    const void* __restrict__ Rf, const void* __restrict__ rbf, const void* __restrict__ bf_,
    const void* __restrict__ Ri, const void* __restrict__ rbi, const void* __restrict__ bi_,
    const void* __restrict__ Rg, const void* __restrict__ rbg, const void* __restrict__ bg_,
    float* __restrict__ rt)
{
    const int f32 = detect_f32(xdet);
    __shared__ float h0f[8][1024];
    const int tid = threadIdx.x;
    const int b0 = blockIdx.y * 8;
    const int z  = blockIdx.z;
    for (int idx = tid; idx < 8 * 1024; idx += 256) {
        int r = idx >> 10, k = idx & 1023;
        h0f[r][k] = ldsc(h0, (b0 + r) * 1024 + k, f32);
    }
    __syncthreads();
    const void* R  = (z == 0) ? Rf  : (z == 1) ? Ri  : Rg;
    const void* rb = (z == 0) ? rbf : (z == 1) ? rbi : rbg;
    const void* bb = (z == 0) ? bf_ : (z == 1) ? bi_ : bg_;
    const int h = blockIdx.x * 256 + tid;
    float acc[8];
#pragma unroll
    for (int i = 0; i < 8; ++i) acc[i] = 0.f;
    for (int k0 = 0; k0 < 1024; k0 += 8) {
        float rf[8];
        if (f32) {
            const float* Rrow = (const float*)R + (size_t)h * 1024;
            float4 a = *(const float4*)(Rrow + k0);
            float4 b = *(const float4*)(Rrow + k0 + 4);
            rf[0] = a.x; rf[1] = a.y; rf[2] = a.z; rf[3] = a.w;
            rf[4] = b.x; rf[5] = b.y; rf[6] = b.z; rf[7] = b.w;
        } else {
            const unsigned short* Rrow = (const unsigned short*)R + (size_t)h * 1024;
            s16x8 rv = *(const s16x8*)(Rrow + k0);
#pragma unroll
            for (int j = 0; j < 8; ++j) rf[j] = bf2f((unsigned short)rv[j]);
        }
#pragma unroll
        for (int b = 0; b < 8; ++b) {
            float4 u0 = *(const float4*)&h0f[b][k0];
            float4 u1 = *(const float4*)&h0f[b][k0 + 4];
            acc[b] += rf[0] * u0.x + rf[1] * u0.y + rf[2] * u0.z + rf[3] * u0.w
                    + rf[4] * u1.x + rf[5] * u1.y + rf[6] * u1.z + rf[7] * u1.w;
        }
    }
    float extra = ldsc(rb, h, f32) + ldsc(bb, h, f32);
    float* outz = rt + (size_t)z * 65536;
#pragma unroll
    for (int b = 0; b < 8; ++b) outz[(b0 + b) * 1024 + h] = acc[b] + extra;
}

__global__ __launch_bounds__(256, 2) void lstm_main(
    const void* __restrict__ x,
    const void* __restrict__ c0,
    const void* __restrict__ Wf,
    const void* __restrict__ Wi,
    const void* __restrict__ Wg,
    const float* __restrict__ rt,
    void* __restrict__ dout)
{
    __shared__ __align__(16) unsigned char smem[33792];
    short* smA  = (short*)smem;
    short* smBf = (short*)(smem + 8192);
    short* smBi = (short*)(smem + 12288);
    short* smBg = (short*)(smem + 16384);

    const int f32 = detect_f32(x);
    const int tid  = threadIdx.x;
    const int lane = tid & 63;
    const int w    = tid >> 6;
    const int wm   = w >> 1;
    const int wn   = w & 1;
    const int col  = lane & 15;
    const int quad = lane >> 4;

    const int m0  = blockIdx.y * 128;
    const int h0t = blockIdx.x * 64;

    const int cA0 = tid, cA1 = tid + 256;
    const int mgA0 = m0 + (cA0 >> 2), mgA1 = m0 + (cA1 >> 2);
    size_t aoff0 = (size_t)((mgA0 & 63) * 512 + (mgA0 >> 6)) * 1024 + (cA0 & 3) * 8;
    size_t aoff1 = (size_t)((mgA1 & 63) * 512 + (mgA1 >> 6)) * 1024 + (cA1 & 3) * 8;
    size_t boff = (size_t)(h0t + (tid >> 2)) * 1024 + (tid & 3) * 8;
    short* dA0 = smA  + cA0 * 8;
    short* dA1 = smA  + cA1 * 8;
    short* dBf = smBf + tid * 8;
    short* dBi = smBi + tid * 8;
    short* dBg = smBg + tid * 8;

    const short* aBase  = smA  + (wm * 64 + col) * 32 + quad * 8;
    const short* bfBase = smBf + (wn * 32 + col) * 32 + quad * 8;
    const short* biBase = smBi + (wn * 32 + col) * 32 + quad * 8;
    const short* bgBase = smBg + (wn * 32 + col) * 32 + quad * 8;

    f32x4 aF[4][2], aI[4][2], aG[4][2];
#pragma unroll
    for (int mi = 0; mi < 4; ++mi)
#pragma unroll
        for (int ni = 0; ni < 2; ++ni) {
            aF[mi][ni] = (f32x4)0.f; aI[mi][ni] = (f32x4)0.f; aG[mi][ni] = (f32x4)0.f;
        }

    for (int kt = 0; kt < 32; ++kt) {
        const size_t ko = (size_t)kt * 32;
        stage8(x,  aoff0 + ko, dA0, f32);
        stage8(x,  aoff1 + ko, dA1, f32);
        stage8(Wf, boff  + ko, dBf, f32);
        stage8(Wi, boff  + ko, dBi, f32);
        stage8(Wg, boff  + ko, dBg, f32);
        __syncthreads();

        s16x8 av[4], bfv[2], biv[2], bgv[2];
#pragma unroll
        for (int mi = 0; mi < 4; ++mi) av[mi] = *(const s16x8*)(aBase + mi * 512);
#pragma unroll
        for (int ni = 0; ni < 2; ++ni) {
            bfv[ni] = *(const s16x8*)(bfBase + ni * 512);
            biv[ni] = *(const s16x8*)(biBase + ni * 512);
            bgv[ni] = *(const s16x8*)(bgBase + ni * 512);
        }
#pragma unroll
        for (int mi = 0; mi < 4; ++mi)
#pragma unroll
            for (int ni = 0; ni < 2; ++ni) {
                aF[mi][ni] = __builtin_amdgcn_mfma_f32_16x16x32_bf16(av[mi], bfv[ni], aF[mi][ni], 0, 0, 0);
                aI[mi][ni] = __builtin_amdgcn_mfma_f32_16x16x32_bf16(av[mi], biv[ni], aI[mi][ni], 0, 0, 0);
                aG[mi][ni] = __builtin_amdgcn_mfma_f32_16x16x32_bf16(av[mi], bgv[ni], aG[mi][ni], 0, 0, 0);
            }
        __syncthreads();
    }

    const float* rtF = rt;
    const float* rtI = rt + 65536;
    const float* rtG = rt + 131072;
    unsigned short* outHb = (unsigned short*)dout;
    unsigned short* outHlb = outHb + 33554432;
    unsigned short* outClb = outHlb + 65536;
    float* outHf = (float*)dout;
    float* outHlf = outHf + 33554432;
    float* outClf = outHlf + 65536;

#pragma unroll
    for (int mi = 0; mi < 4; ++mi) {
#pragma unroll
        for (int ni = 0; ni < 2; ++ni) {
            const int hl = wn * 32 + ni * 16 + col;
            const int h  = h0t + hl;
            const int mbase = wm * 64 + mi * 16 + quad * 4;
            s16x4 packb;
            float4 packf;
#pragma unroll
            for (int r = 0; r < 4; ++r) {
                const int mg = m0 + mbase + r;
                const int b  = mg & 63;
                const int idx = b * 1024 + h;
                float pf = aF[mi][ni][r] + rtF[idx];
                float pi = aI[mi][ni][r] + rtI[idx];
                float pg = aG[mi][ni][r] + rtG[idx];
                float fv = sigm_(pf);
                float iv = sigm_(pi);
                float gv = tanh_(pg);
                float cv = fv * ldsc(c0, idx, f32) + iv * gv;
                float hv = tanh_(cv);
                if (r == 0) { packf.x = hv; } else if (r == 1) { packf.y = hv; }
                else if (r == 2) { packf.z = hv; } else { packf.w = hv; }
                packb[r] = (short)f2bf(hv);
                if ((mg >> 6) == 511) {
                    if (f32) { outHlf[idx] = hv; outClf[idx] = cv; }
                    else     { outHlb[idx] = f2bf(hv); outClb[idx] = f2bf(cv); }
                }
            }
            if (f32) {
                float* ldsTf = (float*)(smem + (size_t)hl * 528);
                *(float4*)(ldsTf + mbase) = packf;
            } else {
                *(s16x4*)(smem + (size_t)hl * 272 + mbase * 2) = packb;
            }
        }
    }
    __syncthreads();

    const int hl = tid >> 2;
    const int ch = tid & 3;
    if (f32) {
        float* obase = outHf + (size_t)(h0t + hl) * 32768 + m0 + ch * 32;
        const unsigned char* trow = smem + (size_t)hl * 528 + ch * 128;
#pragma unroll
        for (int j = 0; j < 8; ++j)
            *(float4*)(obase + j * 4) = *(const float4*)(trow + j * 16);
    } else {
        unsigned short* obase = outHb + (size_t)(h0t + hl) * 32768 + m0 + ch * 32;
        const unsigned char* trow = smem + (size_t)hl * 272 + ch * 64;
#pragma unroll
        for (int j = 0; j < 4; ++j)
            *(s16x8*)(obase + j * 8) = *(const s16x8*)(trow + j * 16);
    }
}

extern "C" void kernel_launch(void* const* d_in, const int* in_sizes, int n_in,
                              void* d_out, int out_size, void* d_ws, size_t ws_size,
                              hipStream_t stream) {
    (void)in_sizes; (void)n_in; (void)out_size;
    const void* x   = d_in[0];
    const void* h0  = d_in[1];
    const void* c0  = d_in[2];
    const void* Wf  = d_in[3];
    const void* bf_ = d_in[4];
    const void* Rf  = d_in[5];
    const void* rbf = d_in[6];
    const void* Wi  = d_in[7];
    const void* bi_ = d_in[8];
    const void* Ri  = d_in[9];
    const void* rbi = d_in[10];
    const void* Wg  = d_in[11];
    const void* bg_ = d_in[12];
    const void* Rg  = d_in[13];
    const void* rbg = d_in[14];
    // d_in[15..18] = Wo, bo, Ro, rbo — dead in the reference, never read.

    // ws layout: xb bf16 [32768][1024] (64 MB) | wb bf16 [3][1024][1024] (6 MB) | rt fp32 (768 KB)
    const size_t NEED = 67108864ull + 6291456ull + 786432ull;
    if (ws_size >= NEED) {
        unsigned short* xb = (unsigned short*)d_ws;
        unsigned short* wbp = xb + 33554432ull;
        float* rt = (float*)(wbp + 3145728ull);
        cvt_kernel<<<dim3(17920), 256, 0, stream>>>(x, Wf, Wi, Wg, xb, wbp);
        rprep2<<<dim3(64, 3), 256, 0, stream>>>(x, h0, Rf, rbf, bf_, Ri, rbi, bi_, Rg, rbg, bg_, rt);
        lstm_main2<<<dim3(16, 256), 256, 0, stream>>>(x, c0, xb, wbp, rt, d_out);
    } else {
        float* rt = (float*)d_ws;
        rprep_kernel<<<dim3(4, 8, 3), 256, 0, stream>>>(x, h0, Rf, rbf, bf_, Ri, rbi, bi_, Rg, rbg, bg_, rt);
        lstm_main<<<dim3(16, 256), 256, 0, stream>>>(x, c0, Wf, Wi, Wg, rt, d_out);
    }
}

// Round 2
// 563.969 us; speedup vs baseline: 1.7640x; 1.0382x over previous
//
#include <hip/hip_runtime.h>
#include <cstdint>

// Problem: B=64, T=512, I=K=1024, H=1024.
// Reference collapses to: rtot_z = h0@R_z^T + rb_z + b_z  (z in {f,i,g}; o-gate dead)
//   gate_z[m',h] = x_perm[m'] . W_z^T + rtot_z[b,h]   with m' = t*64 + b
//   c = sig(f)*c0 + sig(i)*tanh(g); hidden[h, m'] = tanh(c); last-t -> h_last, c_last.
//
// v3 this round:
//   - cvt no longer permutes x (the old (t*64+b)-major write had a 128KB stride
//     between concurrent blocks -> HBM channel camping, ~8x write slowdown, ~280us).
//     xb keeps x's native [b][t][k] row order; lstm_main2 performs the m'->(b,t)
//     permutation in the per-lane GLOBAL source address of global_load_lds (free).
//   - cvt + rprep fused into one dispatch (rprep blocks ride along, overlapping).
//   - lstm_main2 unchanged except A-source row computation.

typedef short s16x8 __attribute__((ext_vector_type(8)));
typedef short s16x4 __attribute__((ext_vector_type(4)));
typedef float f32x4 __attribute__((ext_vector_type(4)));

static __device__ __forceinline__ float bf2f(unsigned short u) {
    union { unsigned int i; float f; } v; v.i = ((unsigned int)u) << 16; return v.f;
}
static __device__ __forceinline__ unsigned short f2bf(float f) {
    union { float f; unsigned int i; } v; v.f = f;
    unsigned int u = v.i;
    return (unsigned short)((u + 0x7fffu + ((u >> 16) & 1u)) >> 16);
}
static __device__ __forceinline__ float sigm_(float x) { return 1.0f / (1.0f + __expf(-x)); }
static __device__ __forceinline__ float tanh_(float x) { return 1.0f - 2.0f / (1.0f + __expf(2.0f * x)); }

// Detect fp32 vs bf16 storage (wave-uniform, deterministic).
static __device__ __forceinline__ int detect_f32(const void* x) {
    const unsigned int* u = (const unsigned int*)x;
    int c = 0;
#pragma unroll
    for (int i = 0; i < 16; ++i) {
        unsigned int e = (u[i] >> 23) & 255u;
        c += (e >= 100u && e <= 140u) ? 1 : 0;
    }
    return c >= 8;
}

static __device__ __forceinline__ float ldsc(const void* p, int i, int f32) {
    return f32 ? ((const float*)p)[i] : bf2f(((const unsigned short*)p)[i]);
}

static __device__ __forceinline__ float4 load4f(const void* p, size_t eoff, int f32) {
    if (f32) return *(const float4*)((const float*)p + eoff);
    s16x4 v = *(const s16x4*)((const unsigned short*)p + eoff);
    return make_float4(bf2f((unsigned short)v[0]), bf2f((unsigned short)v[1]),
                       bf2f((unsigned short)v[2]), bf2f((unsigned short)v[3]));
}

// 16B direct global->LDS (DMA, no VGPR roundtrip). LDS dest must be linear in
// lane order within each wave (wave-uniform base + lane*16) -- caller guarantees.
static __device__ __forceinline__ void gl_lds16(const void* g, void* l) {
    __builtin_amdgcn_global_load_lds(
        (const __attribute__((address_space(1))) unsigned int*)g,
        (__attribute__((address_space(3))) unsigned int*)l, 16, 0, 0);
}

// ---------------- fused prep: linear bf16 convert of x,W  +  rprep ----------------
// blocks [0, 17920): copy/convert. 2 rows/block, 128 threads/row, 8 elems/thread.
//   rows 0..32767: x row r -> xb row r (SAME layout, fully linear both sides).
//   rows 32768..35839: W rows (3 gates) -> wb.
// blocks [17920, 18112): rprep — rt[z][b][h] = h0[b].R_z[h] + rb_z[h] + b_z[h].
//   pb = bid-17920: hb = (pb&63)*16, z = pb>>6.
__global__ __launch_bounds__(256) void prep_fused(
    const void* __restrict__ x,
    const void* __restrict__ Wf, const void* __restrict__ Wi, const void* __restrict__ Wg,
    const void* __restrict__ h0,
    const void* __restrict__ Rf, const void* __restrict__ rbf, const void* __restrict__ bf_,
    const void* __restrict__ Ri, const void* __restrict__ rbi, const void* __restrict__ bi_,
    const void* __restrict__ Rg, const void* __restrict__ rbg, const void* __restrict__ bg_,
    unsigned short* __restrict__ xb, unsigned short* __restrict__ wb,
    float* __restrict__ rt)
{
    __shared__ float h0l[64][132];   // rprep-path only (+4 pad)
    __shared__ float Rl[16][132];
    const int f32 = detect_f32(x);
    const int tid = threadIdx.x;
    const int bid = blockIdx.x;

    if (bid < 17920) {
        // ---- linear convert path ----
        const int r = bid * 2 + (tid >> 7);
        const int c = (tid & 127) << 3;
        const void* src;
        size_t soff;
        unsigned short* dst;
        if (r < 32768) {
            src = x;
            soff = ((size_t)r << 10) + c;
            dst = xb + soff;                       // identity layout
        } else {
            const int wr = r - 32768;              // 0..3071
            const int g = wr >> 10;
            src = (g == 0) ? Wf : (g == 1) ? Wi : Wg;
            soff = ((size_t)(wr & 1023) << 10) + c;
            dst = wb + ((size_t)wr << 10) + c;
        }
        if (f32) {
            const float* s = (const float*)src + soff;
            float4 u0 = *(const float4*)s;
            float4 u1 = *(const float4*)(s + 4);
            s16x8 v;
            v[0] = (short)f2bf(u0.x); v[1] = (short)f2bf(u0.y);
            v[2] = (short)f2bf(u0.z); v[3] = (short)f2bf(u0.w);
            v[4] = (short)f2bf(u1.x); v[5] = (short)f2bf(u1.y);
            v[6] = (short)f2bf(u1.z); v[7] = (short)f2bf(u1.w);
            *(s16x8*)dst = v;
        } else {
            *(s16x8*)dst = *(const s16x8*)((const unsigned short*)src + soff);
        }
        return;
    }

    // ---- rprep path ----
    const int pb = bid - 17920;
    const int z  = pb >> 6;          // 0..2
    const int hb = (pb & 63) * 16;
    const void* R  = (z == 0) ? Rf  : (z == 1) ? Ri  : Rg;
    const void* rb = (z == 0) ? rbf : (z == 1) ? rbi : rbg;
    const void* bb = (z == 0) ? bf_ : (z == 1) ? bi_ : bg_;
    const int hl = tid >> 4;         // 0..15
    const int bq = tid & 15;         // b = bq + 16j
    float acc[4] = {0.f, 0.f, 0.f, 0.f};

    for (int k0 = 0; k0 < 1024; k0 += 128) {
#pragma unroll
        for (int i = 0; i < 8; ++i) {
            int lin = i * 256 + tid;
            int r = lin >> 5, c4 = lin & 31;
            *(float4*)&h0l[r][c4 * 4] = load4f(h0, (size_t)r * 1024 + k0 + c4 * 4, f32);
        }
#pragma unroll
        for (int i = 0; i < 2; ++i) {
            int lin = i * 256 + tid;
            int r = lin >> 5, c4 = lin & 31;
            *(float4*)&Rl[r][c4 * 4] = load4f(R, (size_t)(hb + r) * 1024 + k0 + c4 * 4, f32);
        }
        __syncthreads();
#pragma unroll 8
        for (int k4 = 0; k4 < 32; ++k4) {
            float4 rv = *(const float4*)&Rl[hl][k4 * 4];
#pragma unroll
            for (int j = 0; j < 4; ++j) {
                float4 hv = *(const float4*)&h0l[bq + j * 16][k4 * 4];
                acc[j] += rv.x * hv.x + rv.y * hv.y + rv.z * hv.z + rv.w * hv.w;
            }
        }
        __syncthreads();
    }
    float extra = ldsc(rb, hb + hl, f32) + ldsc(bb, hb + hl, f32);
    float* outz = rt + (size_t)z * 65536;
#pragma unroll
    for (int j = 0; j < 4; ++j)
        outz[(size_t)(bq + j * 16) * 1024 + hb + hl] = acc[j] + extra;
}

// ---------------- main fused GEMM v2 ----------------
// Tile 128 m' x 64 h x 3 gates, BK=64, 4 waves 2x2. global_load_lds staging with
// XOR swizzle: LDS linear dest, inverse-swizzled global src, swizzled ds_read.
// A source rows are the m'->(b,t) permutation of xb's native layout (per-lane addr).
__global__ __launch_bounds__(256, 2) void lstm_main2(
    const void* __restrict__ x,                  // dtype detect only
    const void* __restrict__ c0,
    const unsigned short* __restrict__ xb,       // [64][512][1024] bf16 (native layout)
    const unsigned short* __restrict__ wb,       // [3][1024][1024] bf16
    const float* __restrict__ rt,
    void* __restrict__ dout)
{
    // A 128x64 (16KB) | Bf/Bi/Bg 64x64 (8KB each) = 40960 B
    // epilogue transpose reuses smem: fp32 64x528 = 33792 B
    __shared__ __align__(16) unsigned char smem[40960];

    const int f32 = detect_f32(x);
    const int tid  = threadIdx.x;
    const int lane = tid & 63;
    const int w    = tid >> 6;
    const int wm   = w >> 1;
    const int wn   = w & 1;
    const int col  = lane & 15;
    const int quad = lane >> 4;

    // XCD-pinning block swizzle: linear dispatch id L; XCD = L%8 owns h-tiles {2x,2x+1};
    // the 16 h-blocks of one m-tile dispatch consecutively (A fetched once per XCD-L2).
    const int L    = blockIdx.x + (blockIdx.y << 4);   // grid (16, 256)
    const int xcd  = L & 7;
    const int s    = L >> 3;
    const int hblk = (xcd << 1) | (s & 1);
    const int mblk = s >> 1;
    const int m0   = mblk << 7;
    const int h0t  = hblk << 6;

    // staging descriptors: 16B chunks, LDS linear, global source pre-swizzled.
    // A source row in xb's native layout: m' = m0+row -> xrow = (m'&63)*512 + (m'>>6).
    int   cA[4]; size_t gA[4];
#pragma unroll
    for (int i = 0; i < 4; ++i) {
        const int ci = tid + (i << 8);
        const int row = ci >> 3, kc = ci & 7;
        const int mg = m0 + row;
        const int xrow = ((mg & 63) << 9) + (mg >> 6);
        cA[i] = ci << 4;
        gA[i] = ((size_t)xrow << 10) + (size_t)((kc ^ (row & 7)) << 3);
    }
    int   cB[2]; size_t gB[2];
#pragma unroll
    for (int i = 0; i < 2; ++i) {
        const int ci = tid + (i << 8);
        const int row = ci >> 3, kc = ci & 7;
        cB[i] = ci << 4;
        gB[i] = ((size_t)(h0t + row) << 10) + (size_t)((kc ^ (row & 7)) << 3);
    }

    // fragment read bases (bytes); rows of 128 B; XOR bits 4-6 by row&7 (= col&7)
    const int xbits = (col & 7) << 4;
    int aRow[4], bRow[2];
#pragma unroll
    for (int mi = 0; mi < 4; ++mi) aRow[mi] = (wm * 64 + mi * 16 + col) << 7;
#pragma unroll
    for (int ni = 0; ni < 2; ++ni) bRow[ni] = (wn * 32 + ni * 16 + col) << 7;

    const unsigned short* wf = wb;
    const unsigned short* wi = wb + 1048576;
    const unsigned short* wg = wb + 2097152;

    f32x4 aF[4][2], aI[4][2], aG[4][2];
#pragma unroll
    for (int mi = 0; mi < 4; ++mi)
#pragma unroll
        for (int ni = 0; ni < 2; ++ni) {
            aF[mi][ni] = (f32x4)0.f; aI[mi][ni] = (f32x4)0.f; aG[mi][ni] = (f32x4)0.f;
        }

    for (int kt = 0; kt < 16; ++kt) {
        const size_t k0 = (size_t)kt << 6;
#pragma unroll
        for (int i = 0; i < 4; ++i)
            gl_lds16(xb + gA[i] + k0, smem + cA[i]);
#pragma unroll
        for (int i = 0; i < 2; ++i) {
            gl_lds16(wf + gB[i] + k0, smem + 16384 + cB[i]);
            gl_lds16(wi + gB[i] + k0, smem + 24576 + cB[i]);
            gl_lds16(wg + gB[i] + k0, smem + 32768 + cB[i]);
        }
        __syncthreads();                        // drains vmcnt -> LDS ready
#pragma unroll
        for (int kh = 0; kh < 2; ++kh) {
            const int cb = (((kh << 6) + (quad << 4)) ^ xbits);
            s16x8 av[4], bfv[2], biv[2], bgv[2];
#pragma unroll
            for (int mi = 0; mi < 4; ++mi)
                av[mi] = *(const s16x8*)(smem + aRow[mi] + cb);
#pragma unroll
            for (int ni = 0; ni < 2; ++ni) {
                bfv[ni] = *(const s16x8*)(smem + 16384 + bRow[ni] + cb);
                biv[ni] = *(const s16x8*)(smem + 24576 + bRow[ni] + cb);
                bgv[ni] = *(const s16x8*)(smem + 32768 + bRow[ni] + cb);
            }
#pragma unroll
            for (int mi = 0; mi < 4; ++mi)
#pragma unroll
                for (int ni = 0; ni < 2; ++ni) {
                    aF[mi][ni] = __builtin_amdgcn_mfma_f32_16x16x32_bf16(av[mi], bfv[ni], aF[mi][ni], 0, 0, 0);
                    aI[mi][ni] = __builtin_amdgcn_mfma_f32_16x16x32_bf16(av[mi], biv[ni], aI[mi][ni], 0, 0, 0);
                    aG[mi][ni] = __builtin_amdgcn_mfma_f32_16x16x32_bf16(av[mi], bgv[ni], aG[mi][ni], 0, 0, 0);
                }
        }
        __syncthreads();
    }

    // ---- epilogue ----
    const float* rtF = rt;
    const float* rtI = rt + 65536;
    const float* rtG = rt + 131072;
    unsigned short* outHb = (unsigned short*)dout;
    unsigned short* outHlb = outHb + 33554432;
    unsigned short* outClb = outHlb + 65536;
    float* outHf = (float*)dout;
    float* outHlf = outHf + 33554432;
    float* outClf = outHlf + 65536;

#pragma unroll
    for (int mi = 0; mi < 4; ++mi) {
#pragma unroll
        for (int ni = 0; ni < 2; ++ni) {
            const int hl = wn * 32 + ni * 16 + col;
            const int h  = h0t + hl;
            const int mbase = wm * 64 + mi * 16 + quad * 4;
            s16x4 packb;
            float4 packf;
#pragma unroll
            for (int r = 0; r < 4; ++r) {
                const int mg = m0 + mbase + r;
                const int b  = mg & 63;
                const int idx = b * 1024 + h;
                float pf = aF[mi][ni][r] + rtF[idx];
                float pi = aI[mi][ni][r] + rtI[idx];
                float pg = aG[mi][ni][r] + rtG[idx];
                float fv = sigm_(pf);
                float iv = sigm_(pi);
                float gv = tanh_(pg);
                float cv = fv * ldsc(c0, idx, f32) + iv * gv;
                float hv = tanh_(cv);
                if (r == 0) { packf.x = hv; } else if (r == 1) { packf.y = hv; }
                else if (r == 2) { packf.z = hv; } else { packf.w = hv; }
                packb[r] = (short)f2bf(hv);
                if ((mg >> 6) == 511) {
                    if (f32) { outHlf[idx] = hv; outClf[idx] = cv; }
                    else     { outHlb[idx] = f2bf(hv); outClb[idx] = f2bf(cv); }
                }
            }
            if (f32) {
                float* ldsTf = (float*)(smem + (size_t)hl * 528);
                *(float4*)(ldsTf + mbase) = packf;
            } else {
                *(s16x4*)(smem + (size_t)hl * 272 + mbase * 2) = packb;
            }
        }
    }
    __syncthreads();

    const int hl = tid >> 2;
    const int ch = tid & 3;
    if (f32) {
        float* obase = outHf + (size_t)(h0t + hl) * 32768 + m0 + ch * 32;
        const unsigned char* trow = smem + (size_t)hl * 528 + ch * 128;
#pragma unroll
        for (int j = 0; j < 8; ++j)
            *(float4*)(obase + j * 4) = *(const float4*)(trow + j * 16);
    } else {
        unsigned short* obase = outHb + (size_t)(h0t + hl) * 32768 + m0 + ch * 32;
        const unsigned char* trow = smem + (size_t)hl * 272 + ch * 64;
#pragma unroll
        for (int j = 0; j < 4; ++j)
            *(s16x8*)(obase + j * 8) = *(const s16x8*)(trow + j * 16);
    }
}

// ================= v1 fallback (workspace too small) =================
static __device__ __forceinline__ void stage8(const void* base, size_t eoff, short* dst, int f32) {
    if (f32) {
        const float* s = (const float*)base + eoff;
        float4 u0 = *(const float4*)s;
        float4 u1 = *(const float4*)(s + 4);
        s16x8 v;
        v[0] = (short)f2bf(u0.x); v[1] = (short)f2bf(u0.y);
        v[2] = (short)f2bf(u0.z); v[3] = (short)f2bf(u0.w);
        v[4] = (short)f2bf(u1.x); v[5] = (short)f2bf(u1.y);
        v[6] = (short)f2bf(u1.z); v[7] = (short)f2bf(u1.w);
        *(s16x8*)dst = v;
    } else {
        *(s16x8*)dst = *(const s16x8*)((const unsigned short*)base + eoff);
    }
}

__global__ __launch_bounds__(256) void rprep_kernel(
    const void* __restrict__ xdet,
    const void* __restrict__ h0,
    const void* __restrict__ Rf, const void* __restrict__ rbf, const void* __restrict__ bf_,
    const void* __restrict__ Ri, const void* __restrict__ rbi, const void* __restrict__ bi_,
    const void* __restrict__ Rg, const void* __restrict__ rbg, const void* __restrict__ bg_,
    float* __restrict__ rt)
{
    const int f32 = detect_f32(xdet);
    __shared__ float h0f[8][1024];
    const int tid = threadIdx.x;
    const int b0 = blockIdx.y * 8;
    const int z  = blockIdx.z;
    for (int idx = tid; idx < 8 * 1024; idx += 256) {
        int r = idx >> 10, k = idx & 1023;
        h0f[r][k] = ldsc(h0, (b0 + r) * 1024 + k, f32);
    }
    __syncthreads();
    const void* R  = (z == 0) ? Rf  : (z == 1) ? Ri  : Rg;
    const void* rb = (z == 0) ? rbf : (z == 1) ? rbi : rbg;
    const void* bb = (z == 0) ? bf_ : (z == 1) ? bi_ : bg_;
    const int h = blockIdx.x * 256 + tid;
    float acc[8];
#pragma unroll
    for (int i = 0; i < 8; ++i) acc[i] = 0.f;
    for (int k0 = 0; k0 < 1024; k0 += 8) {
        float rf[8];
        if (f32) {
            const float* Rrow = (const float*)R + (size_t)h * 1024;
            float4 a = *(const float4*)(Rrow + k0);
            float4 b = *(const float4*)(Rrow + k0 + 4);
            rf[0] = a.x; rf[1] = a.y; rf[2] = a.z; rf[3] = a.w;
            rf[4] = b.x; rf[5] = b.y; rf[6] = b.z; rf[7] = b.w;
        } else {
            const unsigned short* Rrow = (const unsigned short*)R + (size_t)h * 1024;
            s16x8 rv = *(const s16x8*)(Rrow + k0);
#pragma unroll
            for (int j = 0; j < 8; ++j) rf[j] = bf2f((unsigned short)rv[j]);
        }
#pragma unroll
        for (int b = 0; b < 8; ++b) {
            float4 u0 = *(const float4*)&h0f[b][k0];
            float4 u1 = *(const float4*)&h0f[b][k0 + 4];
            acc[b] += rf[0] * u0.x + rf[1] * u0.y + rf[2] * u0.z + rf[3] * u0.w
                    + rf[4] * u1.x + rf[5] * u1.y + rf[6] * u1.z + rf[7] * u1.w;
        }
    }
    float extra = ldsc(rb, h, f32) + ldsc(bb, h, f32);
    float* outz = rt + (size_t)z * 65536;
#pragma unroll
    for (int b = 0; b < 8; ++b) outz[(b0 + b) * 1024 + h] = acc[b] + extra;
}

__global__ __launch_bounds__(256, 2) void lstm_main(
    const void* __restrict__ x,
    const void* __restrict__ c0,
    const void* __restrict__ Wf,
    const void* __restrict__ Wi,
    const void* __restrict__ Wg,
    const float* __restrict__ rt,
    void* __restrict__ dout)
{
    __shared__ __align__(16) unsigned char smem[33792];
    short* smA  = (short*)smem;
    short* smBf = (short*)(smem + 8192);
    short* smBi = (short*)(smem + 12288);
    short* smBg = (short*)(smem + 16384);

    const int f32 = detect_f32(x);
    const int tid  = threadIdx.x;
    const int lane = tid & 63;
    const int w    = tid >> 6;
    const int wm   = w >> 1;
    const int wn   = w & 1;
    const int col  = lane & 15;
    const int quad = lane >> 4;

    const int m0  = blockIdx.y * 128;
    const int h0t = blockIdx.x * 64;

    const int cA0 = tid, cA1 = tid + 256;
    const int mgA0 = m0 + (cA0 >> 2), mgA1 = m0 + (cA1 >> 2);
    size_t aoff0 = (size_t)((mgA0 & 63) * 512 + (mgA0 >> 6)) * 1024 + (cA0 & 3) * 8;
    size_t aoff1 = (size_t)((mgA1 & 63) * 512 + (mgA1 >> 6)) * 1024 + (cA1 & 3) * 8;
    size_t boff = (size_t)(h0t + (tid >> 2)) * 1024 + (tid & 3) * 8;
    short* dA0 = smA  + cA0 * 8;
    short* dA1 = smA  + cA1 * 8;
    short* dBf = smBf + tid * 8;
    short* dBi = smBi + tid * 8;
    short* dBg = smBg + tid * 8;

    const short* aBase  = smA  + (wm * 64 + col) * 32 + quad * 8;
    const short* bfBase = smBf + (wn * 32 + col) * 32 + quad * 8;
    const short* biBase = smBi + (wn * 32 + col) * 32 + quad * 8;
    const short* bgBase = smBg + (wn * 32 + col) * 32 + quad * 8;

    f32x4 aF[4][2], aI[4][2], aG[4][2];
#pragma unroll
    for (int mi = 0; mi < 4; ++mi)
#pragma unroll
        for (int ni = 0; ni < 2; ++ni) {
            aF[mi][ni] = (f32x4)0.f; aI[mi][ni] = (f32x4)0.f; aG[mi][ni] = (f32x4)0.f;
        }

    for (int kt = 0; kt < 32; ++kt) {
        const size_t ko = (size_t)kt * 32;
        stage8(x,  aoff0 + ko, dA0, f32);
        stage8(x,  aoff1 + ko, dA1, f32);
        stage8(Wf, boff  + ko, dBf, f32);
        stage8(Wi, boff  + ko, dBi, f32);
        stage8(Wg, boff  + ko, dBg, f32);
        __syncthreads();

        s16x8 av[4], bfv[2], biv[2], bgv[2];
#pragma unroll
        for (int mi = 0; mi < 4; ++mi) av[mi] = *(const s16x8*)(aBase + mi * 512);
#pragma unroll
        for (int ni = 0; ni < 2; ++ni) {
            bfv[ni] = *(const s16x8*)(bfBase + ni * 512);
            biv[ni] = *(const s16x8*)(biBase + ni * 512);
            bgv[ni] = *(const s16x8*)(bgBase + ni * 512);
        }
#pragma unroll
        for (int mi = 0; mi < 4; ++mi)
#pragma unroll
            for (int ni = 0; ni < 2; ++ni) {
                aF[mi][ni] = __builtin_amdgcn_mfma_f32_16x16x32_bf16(av[mi], bfv[ni], aF[mi][ni], 0, 0, 0);
                aI[mi][ni] = __builtin_amdgcn_mfma_f32_16x16x32_bf16(av[mi], biv[ni], aI[mi][ni], 0, 0, 0);
                aG[mi][ni] = __builtin_amdgcn_mfma_f32_16x16x32_bf16(av[mi], bgv[ni], aG[mi][ni], 0, 0, 0);
            }
        __syncthreads();
    }

    const float* rtF = rt;
    const float* rtI = rt + 65536;
    const float* rtG = rt + 131072;
    unsigned short* outHb = (unsigned short*)dout;
    unsigned short* outHlb = outHb + 33554432;
    unsigned short* outClb = outHlb + 65536;
    float* outHf = (float*)dout;
    float* outHlf = outHf + 33554432;
    float* outClf = outHlf + 65536;

#pragma unroll
    for (int mi = 0; mi < 4; ++mi) {
#pragma unroll
        for (int ni = 0; ni < 2; ++ni) {
            const int hl = wn * 32 + ni * 16 + col;
            const int h  = h0t + hl;
            const int mbase = wm * 64 + mi * 16 + quad * 4;
            s16x4 packb;
            float4 packf;
#pragma unroll
            for (int r = 0; r < 4; ++r) {
                const int mg = m0 + mbase + r;
                const int b  = mg & 63;
                const int idx = b * 1024 + h;
                float pf = aF[mi][ni][r] + rtF[idx];
                float pi = aI[mi][ni][r] + rtI[idx];
                float pg = aG[mi][ni][r] + rtG[idx];
                float fv = sigm_(pf);
                float iv = sigm_(pi);
                float gv = tanh_(pg);
                float cv = fv * ldsc(c0, idx, f32) + iv * gv;
                float hv = tanh_(cv);
                if (r == 0) { packf.x = hv; } else if (r == 1) { packf.y = hv; }
                else if (r == 2) { packf.z = hv; } else { packf.w = hv; }
                packb[r] = (short)f2bf(hv);
                if ((mg >> 6) == 511) {
                    if (f32) { outHlf[idx] = hv; outClf[idx] = cv; }
                    else     { outHlb[idx] = f2bf(hv); outClb[idx] = f2bf(cv); }
                }
            }
            if (f32) {
                float* ldsTf = (float*)(smem + (size_t)hl * 528);
                *(float4*)(ldsTf + mbase) = packf;
            } else {
                *(s16x4*)(smem + (size_t)hl * 272 + mbase * 2) = packb;
            }
        }
    }
    __syncthreads();

    const int hl = tid >> 2;
    const int ch = tid & 3;
    if (f32) {
        float* obase = outHf + (size_t)(h0t + hl) * 32768 + m0 + ch * 32;
        const unsigned char* trow = smem + (size_t)hl * 528 + ch * 128;
#pragma unroll
        for (int j = 0; j < 8; ++j)
            *(float4*)(obase + j * 4) = *(const float4*)(trow + j * 16);
    } else {
        unsigned short* obase = outHb + (size_t)(h0t + hl) * 32768 + m0 + ch * 32;
        const unsigned char* trow = smem + (size_t)hl * 272 + ch * 64;
#pragma unroll
        for (int j = 0; j < 4; ++j)
            *(s16x8*)(obase + j * 8) = *(const s16x8*)(trow + j * 16);
    }
}

extern "C" void kernel_launch(void* const* d_in, const int* in_sizes, int n_in,
                              void* d_out, int out_size, void* d_ws, size_t ws_size,
                              hipStream_t stream) {
    (void)in_sizes; (void)n_in; (void)out_size;
    const void* x   = d_in[0];
    const void* h0  = d_in[1];
    const void* c0  = d_in[2];
    const void* Wf  = d_in[3];
    const void* bf_ = d_in[4];
    const void* Rf  = d_in[5];
    const void* rbf = d_in[6];
    const void* Wi  = d_in[7];
    const void* bi_ = d_in[8];
    const void* Ri  = d_in[9];
    const void* rbi = d_in[10];
    const void* Wg  = d_in[11];
    const void* bg_ = d_in[12];
    const void* Rg  = d_in[13];
    const void* rbg = d_in[14];
    // d_in[15..18] = Wo, bo, Ro, rbo — dead in the reference, never read.

    // ws layout: xb bf16 [32768][1024] (64 MB) | wb bf16 [3][1024][1024] (6 MB) | rt fp32 (768 KB)
    const size_t NEED = 67108864ull + 6291456ull + 786432ull;
    if (ws_size >= NEED) {
        unsigned short* xb = (unsigned short*)d_ws;
        unsigned short* wbp = xb + 33554432ull;
        float* rt = (float*)(wbp + 3145728ull);
        prep_fused<<<dim3(18112), 256, 0, stream>>>(x, Wf, Wi, Wg, h0,
                                                    Rf, rbf, bf_, Ri, rbi, bi_, Rg, rbg, bg_,
                                                    xb, wbp, rt);
        lstm_main2<<<dim3(16, 256), 256, 0, stream>>>(x, c0, xb, wbp, rt, d_out);
    } else {
        float* rt = (float*)d_ws;
        rprep_kernel<<<dim3(4, 8, 3), 256, 0, stream>>>(x, h0, Rf, rbf, bf_, Ri, rbi, bi_, Rg, rbg, bg_, rt);
        lstm_main<<<dim3(16, 256), 256, 0, stream>>>(x, c0, Wf, Wi, Wg, rt, d_out);
    }
}